// Round 6
// baseline (177.200 us; speedup 1.0000x reference)
//
#include <hip/hip_runtime.h>
#include <hip/hip_bf16.h>

typedef __bf16 bf16x8 __attribute__((ext_vector_type(8)));
typedef float  f32x4  __attribute__((ext_vector_type(4)));

constexpr int kNHRZ = 2048, kBATCH = 128, kNU = 64, kNY = 64, kNH = 256, kH = 128;
constexpr int kCHUNK = 64, kNCHUNK = kNHRZ / kCHUNK;   // 32 chunks
constexpr int kTS = 16, kM = 32;                       // 16 t x 2 b rows per subtile
constexpr int kNSUB = kCHUNK / kTS;                    // 4 subtiles per chunk

// Xs stride (bf16 elems). 268: row stride 536B. GEMM2 b128 reads: lw*134 dw
// -> distinct even bank residues, 2-way (free). Writes: lg*4 rows = 2144B
// = 96 mod 128 -> lg groups on disjoint bank octets, 2-way (free).
constexpr int X_STR = 268;
constexpr int SMEM2 = kM * X_STR * 2;  // 17152 B (pass2 only; pass1 uses 0)

__device__ inline bf16x8 cvt8(float4 a, float4 b) {
    bf16x8 v;
    v[0] = (__bf16)a.x; v[1] = (__bf16)a.y; v[2] = (__bf16)a.z; v[3] = (__bf16)a.w;
    v[4] = (__bf16)b.x; v[5] = (__bf16)b.y; v[6] = (__bf16)b.z; v[7] = (__bf16)b.w;
    return v;
}

// ---------------------------------------------------------------------------
// Fused per-chunk kernel, register-resident scan.
// Block = (chunk c, batch pair), 256 threads = 4 waves.
// Wave w owns h-pairs: nt0/1 -> hm = w*32 + {0,16} + lw (real),
//                      nt2/3 -> hm+128 (imag). Rotation is lane-local.
// A-row map: tile mt = batch (bglob+mt), row-in-tile = t_local (0..15).
// MFMA 16x16x32 C/D: col = lane&15 (h), row = (lane>>4)*4 + i (t_local)
//   -> lane holds 4 consecutive t of its own h-pair: register scan +
//      3-shuffle Kogge-Stone prefix across lane-groups (factors l^4, l^8).
// NOTE: __launch_bounds__(256,2) — NOT (256,4): tighter bound spills the
// fragment arrays (R4: +950 MB scratch traffic, 2.5x slower).
// ---------------------------------------------------------------------------
template <bool FINAL>
__global__ __launch_bounds__(256, 2) void scan_mfma(
    const float* __restrict__ U,      // (NHRZ, BATCH, NU)
    const float* __restrict__ lre,    // (H,)
    const float* __restrict__ lim,    // (H,)
    const float* __restrict__ Bmat,   // (NH, NU)
    const float* __restrict__ Wx2y,   // (NY, NH)   [FINAL]
    const float* __restrict__ bx2y,   // (NY,)      [FINAL]
    const float* __restrict__ starts, // (NCHUNK, BATCH, NH) [FINAL]
    float* __restrict__ ends,         // (NCHUNK, BATCH, NH) [!FINAL]
    float* __restrict__ out)          // (NHRZ+1, BATCH, NY) [FINAL]
{
    extern __shared__ char smem[];
    __bf16* Xs = (__bf16*)smem;       // [kM][X_STR]  (FINAL only)

    const int tid  = threadIdx.x;
    const int lane = tid & 63;
    const int w    = tid >> 6;        // wave 0..3
    const int lw   = lane & 15;
    const int lg   = lane >> 4;
    const int c    = blockIdx.x >> 6;         // chunk
    const int bp   = blockIdx.x & 63;         // batch pair
    const int bglob = bp * 2;
    const int t0   = c * kCHUNK;

    // --- lambda constants for the two delta streams (d=0: +0, d=1: +16)
    float l1r[2], l1i[2], l2r[2], l2i[2], l3r[2], l3i[2],
          l4r[2], l4i[2], l8r[2], l8i[2], nfv[2];
#pragma unroll
    for (int d = 0; d < 2; ++d) {
        const int hm = w * 32 + d * 16 + lw;
        const float ab = fabsf(lre[hm]);
        const float r  = expf(-ab);
        const float th = 1.5707963267948966f * lim[hm];
        l1r[d] = r * cosf(th);
        l1i[d] = r * sinf(th);
        l2r[d] = l1r[d]*l1r[d] - l1i[d]*l1i[d];
        l2i[d] = 2.0f * l1r[d] * l1i[d];
        l3r[d] = l2r[d]*l1r[d] - l2i[d]*l1i[d];
        l3i[d] = l2r[d]*l1i[d] + l2i[d]*l1r[d];
        l4r[d] = l2r[d]*l2r[d] - l2i[d]*l2i[d];
        l4i[d] = 2.0f * l2r[d] * l2i[d];
        l8r[d] = l4r[d]*l4r[d] - l4i[d]*l4i[d];
        l8i[d] = 2.0f * l4r[d] * l4i[d];
        nfv[d] = sqrtf(fmaxf(0.0f, 1.0f - expf(-2.0f * ab)));
    }

    // --- B fragments, paired layout: Bf[ks][d] = real rows, Bf[ks][d+2] = imag
    bf16x8 Bf[2][4];
#pragma unroll
    for (int d = 0; d < 2; ++d) {
        const int hre = w * 32 + d * 16 + lw;
#pragma unroll
        for (int ks = 0; ks < 2; ++ks) {
            const float* p0 = Bmat + hre * kNU + ks * 32 + lg * 8;
            const float* p1 = Bmat + (hre + kH) * kNU + ks * 32 + lg * 8;
            float4 a0 = ((const float4*)p0)[0], a1 = ((const float4*)p0)[1];
            float4 b0 = ((const float4*)p1)[0], b1 = ((const float4*)p1)[1];
            const float nf = nfv[d];
            a0.x*=nf; a0.y*=nf; a0.z*=nf; a0.w*=nf;
            a1.x*=nf; a1.y*=nf; a1.z*=nf; a1.w*=nf;
            b0.x*=nf; b0.y*=nf; b0.z*=nf; b0.w*=nf;
            b1.x*=nf; b1.y*=nf; b1.z*=nf; b1.w*=nf;
            Bf[ks][d]     = cvt8(a0, a1);
            Bf[ks][d + 2] = cvt8(b0, b1);
        }
    }

    // --- W fragments + bias (FINAL)
    bf16x8 Wf[8][2];
    float  bias[2] = {0.f, 0.f};
    if constexpr (FINAL) {
#pragma unroll
        for (int nt = 0; nt < 2; ++nt) {
            const int y = (w >> 1) * 32 + nt * 16 + lw;
            bias[nt] = bx2y[y];
#pragma unroll
            for (int ks = 0; ks < 8; ++ks) {
                const float* p = Wx2y + y * kNH + ks * 32 + lg * 8;
                Wf[ks][nt] = cvt8(((const float4*)p)[0], ((const float4*)p)[1]);
            }
        }
    }

    // --- per-lane chunk-carry state, 4 streams [mt][d]
    float xr[2][2], xi[2][2];
#pragma unroll
    for (int mt = 0; mt < 2; ++mt)
#pragma unroll
        for (int d = 0; d < 2; ++d) {
            if constexpr (FINAL) {
                const int hm = w * 32 + d * 16 + lw;
                const size_t sb = ((size_t)c * kBATCH + bglob + mt) * kNH;
                xr[mt][d] = starts[sb + hm];
                xi[mt][d] = starts[sb + hm + kH];
            } else {
                xr[mt][d] = 0.0f;
                xi[mt][d] = 0.0f;
            }
        }

#pragma unroll 1
    for (int s = 0; s < kNSUB; ++s) {
        // ---- A fragments straight from global (row t = t0+s*16+lw)
        bf16x8 A[2][2];  // [mt][ks]
#pragma unroll
        for (int mt = 0; mt < 2; ++mt)
#pragma unroll
            for (int ks = 0; ks < 2; ++ks) {
                const float* p = U + ((size_t)(t0 + s * kTS + lw) * kBATCH +
                                      bglob + mt) * kNU + ks * 32 + lg * 8;
                A[mt][ks] = cvt8(((const float4*)p)[0], ((const float4*)p)[1]);
            }

        // ---- GEMM1 into registers: acc[mt][nt], row=t_local, col=h
        f32x4 acc[2][4] = {};
#pragma unroll
        for (int ks = 0; ks < 2; ++ks)
#pragma unroll
            for (int mt = 0; mt < 2; ++mt)
#pragma unroll
                for (int nt = 0; nt < 4; ++nt)
                    acc[mt][nt] = __builtin_amdgcn_mfma_f32_16x16x32_bf16(
                        A[mt][ks], Bf[ks][nt], acc[mt][nt], 0, 0, 0);

        if constexpr (FINAL) {
            if (s > 0) __syncthreads();  // prev GEMM2's Xs reads done (WAR)
        }

        // ---- register scan: per stream, local 4-step scan + lane-group prefix
#pragma unroll
        for (int mt = 0; mt < 2; ++mt)
#pragma unroll
            for (int d = 0; d < 2; ++d) {
                float Lr[4], Li[4];
                Lr[0] = acc[mt][d][0];
                Li[0] = acc[mt][d + 2][0];
#pragma unroll
                for (int i = 1; i < 4; ++i) {
                    Lr[i] = fmaf(l1r[d], Lr[i-1], fmaf(-l1i[d], Li[i-1], acc[mt][d][i]));
                    Li[i] = fmaf(l1i[d], Lr[i-1], fmaf( l1r[d], Li[i-1], acc[mt][d+2][i]));
                }
                // inject carry-in at lg=0, shifted local ends elsewhere
                float vr = __shfl(Lr[3], (lane - 16) & 63);
                float vi = __shfl(Li[3], (lane - 16) & 63);
                float Tr = (lg == 0) ? xr[mt][d] : vr;
                float Ti = (lg == 0) ? xi[mt][d] : vi;
                // Kogge-Stone step 1 (factor l^4)
                float ur = __shfl(Tr, (lane - 16) & 63);
                float ui = __shfl(Ti, (lane - 16) & 63);
                float t1r = fmaf(l4r[d], ur, fmaf(-l4i[d], ui, Tr));
                float t1i = fmaf(l4i[d], ur, fmaf( l4r[d], ui, Ti));
                Tr = (lg >= 1) ? t1r : Tr;
                Ti = (lg >= 1) ? t1i : Ti;
                // step 2 (factor l^8)
                ur = __shfl(Tr, (lane - 32) & 63);
                ui = __shfl(Ti, (lane - 32) & 63);
                t1r = fmaf(l8r[d], ur, fmaf(-l8i[d], ui, Tr));
                t1i = fmaf(l8i[d], ur, fmaf( l8r[d], ui, Ti));
                Tr = (lg >= 2) ? t1r : Tr;
                Ti = (lg >= 2) ? t1i : Ti;
                // T = true state entering this lane's 4 steps.
                // chunk-carry: state after this group, broadcast from lg=3
                const float spr = fmaf(l4r[d], Tr, fmaf(-l4i[d], Ti, Lr[3]));
                const float spi = fmaf(l4i[d], Tr, fmaf( l4r[d], Ti, Li[3]));
                xr[mt][d] = __shfl(spr, lw | 48);
                xi[mt][d] = __shfl(spi, lw | 48);

                if constexpr (FINAL) {
                    // x_t = L[i] + l^{i+1} * T  -> Xs (bf16)
                    const float pr[4] = {l1r[d], l2r[d], l3r[d], l4r[d]};
                    const float pi[4] = {l1i[d], l2i[d], l3i[d], l4i[d]};
                    const int hre = w * 32 + d * 16 + lw;
#pragma unroll
                    for (int i = 0; i < 4; ++i) {
                        const float xtr = fmaf(pr[i], Tr, fmaf(-pi[i], Ti, Lr[i]));
                        const float xti = fmaf(pi[i], Tr, fmaf( pr[i], Ti, Li[i]));
                        const int m = mt * 16 + lg * 4 + i;
                        Xs[m * X_STR + hre]      = (__bf16)xtr;
                        Xs[m * X_STR + hre + kH] = (__bf16)xti;
                    }
                }
            }

        if constexpr (FINAL) {
            __syncthreads();  // Xs ready
            // ---- GEMM2: wave w: batch tile mtY=w&1, y-base (w>>1)*32, K=256
            f32x4 acc2[2] = {};
            const int mtY = w & 1;
#pragma unroll
            for (int ks = 0; ks < 8; ++ks) {
                bf16x8 a = *(const bf16x8*)&Xs[(mtY * 16 + lw) * X_STR + ks * 32 + lg * 8];
                acc2[0] = __builtin_amdgcn_mfma_f32_16x16x32_bf16(a, Wf[ks][0], acc2[0], 0, 0, 0);
                acc2[1] = __builtin_amdgcn_mfma_f32_16x16x32_bf16(a, Wf[ks][1], acc2[1], 0, 0, 0);
            }
#pragma unroll
            for (int i = 0; i < 4; ++i) {
                const int t = t0 + s * kTS + lg * 4 + i;
                const int b = bglob + mtY;
                float* orow = out + ((size_t)(1 + t) * kBATCH + b) * kNY +
                              (w >> 1) * 32 + lw;
                orow[0]  = acc2[0][i] + bias[0];
                orow[16] = acc2[1][i] + bias[1];
            }
        }
    }

    if constexpr (!FINAL) {
#pragma unroll
        for (int mt = 0; mt < 2; ++mt)
#pragma unroll
            for (int d = 0; d < 2; ++d) {
                const int hm = w * 32 + d * 16 + lw;
                const size_t eb = ((size_t)c * kBATCH + bglob + mt) * kNH;
                ends[eb + hm]      = xr[mt][d];
                ends[eb + hm + kH] = xi[mt][d];
            }
    }
}

// ---------------------------------------------------------------------------
// Sequential combine over chunks + x0 computation.
// ---------------------------------------------------------------------------
__global__ __launch_bounds__(128) void combine_kernel(
    const float* __restrict__ y0, const float* __restrict__ Wy2x,
    const float* __restrict__ by2x, const float* __restrict__ lre,
    const float* __restrict__ lim, const float* __restrict__ ends,
    float* __restrict__ starts)
{
    const int b  = blockIdx.x;
    const int hm = threadIdx.x;

    const float ab = fabsf(lre[hm]);
    const float r  = expf(-ab);
    const float th = 1.5707963267948966f * lim[hm];
    float lr = r * cosf(th);
    float li = r * sinf(th);
    float pr = lr, pi = li;
#pragma unroll
    for (int k = 0; k < 6; ++k) {  // lambda^64
        const float nr = pr * pr - pi * pi;
        const float ni = 2.0f * pr * pi;
        pr = nr; pi = ni;
    }

    float s1 = by2x[hm];
    float s2 = by2x[hm + kH];
#pragma unroll 8
    for (int q = 0; q < kNY; ++q) {
        const float yv = y0[b * kNY + q];
        s1 = fmaf(Wy2x[hm * kNY + q], yv, s1);
        s2 = fmaf(Wy2x[(hm + kH) * kNY + q], yv, s2);
    }

    for (int c = 0; c < kNCHUNK; ++c) {
        const size_t base = ((size_t)c * kBATCH + b) * kNH;
        starts[base + hm]      = s1;
        starts[base + hm + kH] = s2;
        const float e1 = ends[base + hm];
        const float e2 = ends[base + hm + kH];
        const float n1 = fmaf(pr, s1, fmaf(-pi, s2, e1));
        const float n2 = fmaf(pi, s1, fmaf(pr, s2, e2));
        s1 = n1; s2 = n2;
    }
}

// Y row 0 = Wx2y @ x0 + bx2y  (x0 = starts[c=0])
__global__ __launch_bounds__(64) void y0_kernel(
    const float* __restrict__ starts, const float* __restrict__ Wx2y,
    const float* __restrict__ bx2y, float* __restrict__ out)
{
    const int b = blockIdx.x;
    const int y = threadIdx.x;
    const float* x0 = starts + (size_t)b * kNH;
    float acc = bx2y[y];
#pragma unroll 4
    for (int h = 0; h < kNH; h += 4) {
        float4 xv = *(const float4*)&x0[h];
        float4 wv = *(const float4*)&Wx2y[y * kNH + h];
        acc = fmaf(wv.x, xv.x, acc);
        acc = fmaf(wv.y, xv.y, acc);
        acc = fmaf(wv.z, xv.z, acc);
        acc = fmaf(wv.w, xv.w, acc);
    }
    out[(size_t)b * kNY + y] = acc;
}

extern "C" void kernel_launch(void* const* d_in, const int* in_sizes, int n_in,
                              void* d_out, int out_size, void* d_ws, size_t ws_size,
                              hipStream_t stream) {
    const float* y0   = (const float*)d_in[0];
    const float* U    = (const float*)d_in[1];
    const float* lre  = (const float*)d_in[2];
    const float* lim  = (const float*)d_in[3];
    const float* Bmat = (const float*)d_in[4];
    const float* Wy2x = (const float*)d_in[5];
    const float* by2x = (const float*)d_in[6];
    const float* Wx2y = (const float*)d_in[7];
    const float* bx2y = (const float*)d_in[8];
    float* out = (float*)d_out;

    float* ends   = (float*)d_ws;                          // 4 MB
    float* starts = ends + (size_t)kNCHUNK * kBATCH * kNH; // 4 MB

    const int grid = kNCHUNK * (kBATCH / 2);  // 2048 blocks

    scan_mfma<false><<<grid, 256, 0, stream>>>(
        U, lre, lim, Bmat, nullptr, nullptr, nullptr, ends, nullptr);
    combine_kernel<<<kBATCH, 128, 0, stream>>>(
        y0, Wy2x, by2x, lre, lim, ends, starts);
    y0_kernel<<<kBATCH, 64, 0, stream>>>(starts, Wx2y, bx2y, out);
    scan_mfma<true><<<grid, 256, SMEM2, stream>>>(
        U, lre, lim, Bmat, Wx2y, bx2y, starts, nullptr, out);
}

// Round 9
// 134.637 us; speedup vs baseline: 1.3161x; 1.3161x over previous
//
#include <hip/hip_runtime.h>
#include <hip/hip_bf16.h>

typedef __bf16 bf16x8 __attribute__((ext_vector_type(8)));
typedef float  f32x4  __attribute__((ext_vector_type(4)));

constexpr int kNHRZ = 2048, kBATCH = 128, kNU = 64, kNY = 64, kNH = 256, kH = 128;
constexpr int kCHUNK = 64, kNCHUNK = kNHRZ / kCHUNK;   // 32 chunks
constexpr int kTS = 16, kM = 32;                       // 16 t x 2 b rows per subtile
constexpr int kNSUB = kCHUNK / kTS;                    // 4 subtiles per chunk

// LDS strides (elements)
constexpr int U_STR = 72;    // bf16, 144 B rows (R2-R5 proven pattern)
constexpr int X_STR = 268;   // bf16, 536 B rows (R6 proven pattern)

constexpr int OFF_US = 0;                          // U dbuf: 2*32*72*2 = 9216 B
constexpr int OFF_XS = 2 * kM * U_STR * 2;         // 9216
constexpr int SMEM1  = OFF_XS;                     // pass1: 9216 B
constexpr int SMEM2  = OFF_XS + kM * X_STR * 2;    // pass2: 26368 B

__device__ inline bf16x8 pack8(float4 a, float4 b) {
    bf16x8 v;
    v[0] = (__bf16)a.x; v[1] = (__bf16)a.y; v[2] = (__bf16)a.z; v[3] = (__bf16)a.w;
    v[4] = (__bf16)b.x; v[5] = (__bf16)b.y; v[6] = (__bf16)b.z; v[7] = (__bf16)b.w;
    return v;
}

// ---------------------------------------------------------------------------
// Fused per-chunk kernel: staged-LDS U (dbuf, coalesced) -> MFMA Bu
// (registers) -> register scan (in-lane 4-step + shfl prefix) ->
// [FINAL] Xs (identity layout, scalar writes — R6-verified) -> MFMA Y.
// Block = (chunk, batch pair), 256 threads = 4 waves.
// Wave w owns h-modes w*32+{0,16}+lw (d=0,1), real nt=d / imag nt=d+2.
// MFMA 16x16x32: A row=lane&15, k=(lane>>4)*8+j; B col=lane&15, same k;
// C/D col=lane&15, row=(lane>>4)*4+i -> lane holds 4 consecutive t of its
// own h-pair.
// Barriers: pass1 = 1/subtile; pass2 = 2/subtile (R6 structure).
// NOTE: __launch_bounds__(256,2) — tighter bounds spill fragments (R4).
// ---------------------------------------------------------------------------
template <bool FINAL>
__global__ __launch_bounds__(256, 2) void scan_mfma(
    const float* __restrict__ U,      // (NHRZ, BATCH, NU)
    const float* __restrict__ lre,    // (H,)
    const float* __restrict__ lim,    // (H,)
    const float* __restrict__ Bmat,   // (NH, NU)
    const float* __restrict__ Wx2y,   // (NY, NH)   [FINAL]
    const float* __restrict__ bx2y,   // (NY,)      [FINAL]
    const float* __restrict__ starts, // (NCHUNK, BATCH, NH) [FINAL]
    float* __restrict__ ends,         // (NCHUNK, BATCH, NH) [!FINAL]
    float* __restrict__ out)          // (NHRZ+1, BATCH, NY) [FINAL]
{
    extern __shared__ char smem[];
    __bf16* Us = (__bf16*)(smem + OFF_US);   // [2][kM][U_STR]
    __bf16* Xs = (__bf16*)(smem + OFF_XS);   // [kM][X_STR]  (FINAL, single buf)

    const int tid  = threadIdx.x;
    const int lane = tid & 63;
    const int w    = tid >> 6;        // wave 0..3
    const int lw   = lane & 15;
    const int lg   = lane >> 4;
    const int c    = blockIdx.x >> 6;         // chunk
    const int bp   = blockIdx.x & 63;         // batch pair
    const int bglob = bp * 2;
    const int t0   = c * kCHUNK;

    // --- lambda constants for the two streams (d=0: +0, d=1: +16)
    float l1r[2], l1i[2], l2r[2], l2i[2], l3r[2], l3i[2],
          l4r[2], l4i[2], l8r[2], l8i[2], nfv[2];
#pragma unroll
    for (int d = 0; d < 2; ++d) {
        const int hm = w * 32 + d * 16 + lw;
        const float ab = fabsf(lre[hm]);
        const float r  = expf(-ab);
        const float th = 1.5707963267948966f * lim[hm];
        l1r[d] = r * cosf(th);
        l1i[d] = r * sinf(th);
        l2r[d] = l1r[d]*l1r[d] - l1i[d]*l1i[d];
        l2i[d] = 2.0f * l1r[d] * l1i[d];
        l3r[d] = l2r[d]*l1r[d] - l2i[d]*l1i[d];
        l3i[d] = l2r[d]*l1i[d] + l2i[d]*l1r[d];
        l4r[d] = l2r[d]*l2r[d] - l2i[d]*l2i[d];
        l4i[d] = 2.0f * l2r[d] * l2i[d];
        l8r[d] = l4r[d]*l4r[d] - l4i[d]*l4i[d];
        l8i[d] = 2.0f * l4r[d] * l4i[d];
        nfv[d] = sqrtf(fmaxf(0.0f, 1.0f - expf(-2.0f * ab)));
    }

    // --- B fragments, paired layout: Bf[ks][d]=real rows, Bf[ks][d+2]=imag
    bf16x8 Bf[2][4];
#pragma unroll
    for (int d = 0; d < 2; ++d) {
        const int hre = w * 32 + d * 16 + lw;
#pragma unroll
        for (int ks = 0; ks < 2; ++ks) {
            const float* p0 = Bmat + hre * kNU + ks * 32 + lg * 8;
            const float* p1 = Bmat + (hre + kH) * kNU + ks * 32 + lg * 8;
            float4 a0 = ((const float4*)p0)[0], a1 = ((const float4*)p0)[1];
            float4 b0 = ((const float4*)p1)[0], b1 = ((const float4*)p1)[1];
            const float nf = nfv[d];
            a0.x*=nf; a0.y*=nf; a0.z*=nf; a0.w*=nf;
            a1.x*=nf; a1.y*=nf; a1.z*=nf; a1.w*=nf;
            b0.x*=nf; b0.y*=nf; b0.z*=nf; b0.w*=nf;
            b1.x*=nf; b1.y*=nf; b1.z*=nf; b1.w*=nf;
            Bf[ks][d]     = pack8(a0, a1);
            Bf[ks][d + 2] = pack8(b0, b1);
        }
    }

    // --- W fragments (identity columns, R6-verified) + bias (FINAL)
    bf16x8 Wf[8][2];
    float  bias[2] = {0.f, 0.f};
    if constexpr (FINAL) {
#pragma unroll
        for (int nt = 0; nt < 2; ++nt) {
            const int y = (w >> 1) * 32 + nt * 16 + lw;
            bias[nt] = bx2y[y];
#pragma unroll
            for (int ks = 0; ks < 8; ++ks) {
                const float* p = Wx2y + y * kNH + ks * 32 + lg * 8;
                Wf[ks][nt] = pack8(((const float4*)p)[0], ((const float4*)p)[1]);
            }
        }
    }

    // --- per-lane chunk-carry state, 4 streams [mt][d]
    float xr[2][2], xi[2][2];
#pragma unroll
    for (int mt = 0; mt < 2; ++mt)
#pragma unroll
        for (int d = 0; d < 2; ++d) {
            if constexpr (FINAL) {
                const int hm = w * 32 + d * 16 + lw;
                const size_t sb = ((size_t)c * kBATCH + bglob + mt) * kNH;
                xr[mt][d] = starts[sb + hm];
                xi[mt][d] = starts[sb + hm + kH];
            } else {
                xr[mt][d] = 0.0f;
                xi[mt][d] = 0.0f;
            }
        }

    // --- U staging map: thread -> (sm = tid>>3, sq = tid&7); Us row
    // srow = st_b*16 + st_t so GEMM1 tile mt has pure-t rows.
    const int sm = tid >> 3, sq = tid & 7;
    const int st_t = sm & 15, st_b = sm >> 4;
    const float* uptr =
        U + ((size_t)(t0 + st_t) * kBATCH + bglob + st_b) * kNU + sq * 8;
    const int srow = st_b * 16 + st_t;

    // prologue: stage subtile 0 into buffer 0
    {
        float4 u0 = ((const float4*)uptr)[0];
        float4 u1 = ((const float4*)uptr)[1];
        *(bf16x8*)&Us[srow * U_STR + sq * 8] = pack8(u0, u1);
    }
    __syncthreads();

#pragma unroll 1
    for (int s = 0; s < kNSUB; ++s) {
        const int cur = s & 1;
        __bf16* Uc = Us + cur * (kM * U_STR);
        __bf16* Un = Us + (cur ^ 1) * (kM * U_STR);

        // ---- issue next-subtile global loads early (hidden under compute)
        float4 u0, u1;
        if (s + 1 < kNSUB) {
            const float* p = uptr + (size_t)(s + 1) * kTS * kBATCH * kNU;
            u0 = ((const float4*)p)[0];
            u1 = ((const float4*)p)[1];
        }

        // ---- A fragments from LDS (row = mt*16 + lw, pure t rows)
        bf16x8 A[2][2];
#pragma unroll
        for (int mt = 0; mt < 2; ++mt)
#pragma unroll
            for (int ks = 0; ks < 2; ++ks)
                A[mt][ks] = *(const bf16x8*)&Uc[(mt * 16 + lw) * U_STR + ks * 32 + lg * 8];

        // ---- GEMM1 into registers: acc[mt][nt], row=t_local, col=h
        f32x4 acc[2][4] = {};
#pragma unroll
        for (int ks = 0; ks < 2; ++ks)
#pragma unroll
            for (int mt = 0; mt < 2; ++mt)
#pragma unroll
                for (int nt = 0; nt < 4; ++nt)
                    acc[mt][nt] = __builtin_amdgcn_mfma_f32_16x16x32_bf16(
                        A[mt][ks], Bf[ks][nt], acc[mt][nt], 0, 0, 0);

        if constexpr (FINAL) {
            if (s > 0) __syncthreads();  // sync1: prev GEMM2's Xs reads done (WAR)
        }

        // ---- register scan: in-lane 4-step + shfl prefix per stream
#pragma unroll
        for (int mt = 0; mt < 2; ++mt)
#pragma unroll
            for (int d = 0; d < 2; ++d) {
                float Lr[4], Li[4];
                Lr[0] = acc[mt][d][0];
                Li[0] = acc[mt][d + 2][0];
#pragma unroll
                for (int i = 1; i < 4; ++i) {
                    Lr[i] = fmaf(l1r[d], Lr[i-1], fmaf(-l1i[d], Li[i-1], acc[mt][d][i]));
                    Li[i] = fmaf(l1i[d], Lr[i-1], fmaf( l1r[d], Li[i-1], acc[mt][d+2][i]));
                }
                // inject carry at lg=0, shifted local ends elsewhere
                float vr = __shfl(Lr[3], (lane - 16) & 63);
                float vi = __shfl(Li[3], (lane - 16) & 63);
                float Tr = (lg == 0) ? xr[mt][d] : vr;
                float Ti = (lg == 0) ? xi[mt][d] : vi;
                // Kogge-Stone step 1 (factor l^4)
                float ur = __shfl(Tr, (lane - 16) & 63);
                float ui = __shfl(Ti, (lane - 16) & 63);
                float t1r = fmaf(l4r[d], ur, fmaf(-l4i[d], ui, Tr));
                float t1i = fmaf(l4i[d], ur, fmaf( l4r[d], ui, Ti));
                Tr = (lg >= 1) ? t1r : Tr;
                Ti = (lg >= 1) ? t1i : Ti;
                // step 2 (factor l^8)
                ur = __shfl(Tr, (lane - 32) & 63);
                ui = __shfl(Ti, (lane - 32) & 63);
                t1r = fmaf(l8r[d], ur, fmaf(-l8i[d], ui, Tr));
                t1i = fmaf(l8i[d], ur, fmaf( l8r[d], ui, Ti));
                Tr = (lg >= 2) ? t1r : Tr;
                Ti = (lg >= 2) ? t1i : Ti;
                // chunk-carry: state after this lane-group, broadcast from lg=3
                const float spr = fmaf(l4r[d], Tr, fmaf(-l4i[d], Ti, Lr[3]));
                const float spi = fmaf(l4i[d], Tr, fmaf( l4r[d], Ti, Li[3]));
                xr[mt][d] = __shfl(spr, lw | 48);
                xi[mt][d] = __shfl(spi, lw | 48);

                if constexpr (FINAL) {
                    // x_t = L[i] + l^{i+1} * T  -> Xs (bf16, identity layout)
                    const float pr[4] = {l1r[d], l2r[d], l3r[d], l4r[d]};
                    const float pi[4] = {l1i[d], l2i[d], l3i[d], l4i[d]};
                    const int hre = w * 32 + d * 16 + lw;
#pragma unroll
                    for (int i = 0; i < 4; ++i) {
                        const float xtr = fmaf(pr[i], Tr, fmaf(-pi[i], Ti, Lr[i]));
                        const float xti = fmaf(pi[i], Tr, fmaf( pr[i], Ti, Li[i]));
                        const int m = mt * 16 + lg * 4 + i;
                        Xs[m * X_STR + hre]      = (__bf16)xtr;
                        Xs[m * X_STR + hre + kH] = (__bf16)xti;
                    }
                }
            }

        // ---- write next U subtile into the other buffer
        if (s + 1 < kNSUB)
            *(bf16x8*)&Un[srow * U_STR + sq * 8] = pack8(u0, u1);

        __syncthreads();  // sync2: Un staged; Xs ready

        if constexpr (FINAL) {
            // ---- GEMM2: wave w: batch tile mtY=w&1, y-base (w>>1)*32, K=256
            f32x4 acc2[2] = {};
            const int mtY = w & 1;
#pragma unroll
            for (int ks = 0; ks < 8; ++ks) {
                bf16x8 a = *(const bf16x8*)&Xs[(mtY * 16 + lw) * X_STR + ks * 32 + lg * 8];
                acc2[0] = __builtin_amdgcn_mfma_f32_16x16x32_bf16(a, Wf[ks][0], acc2[0], 0, 0, 0);
                acc2[1] = __builtin_amdgcn_mfma_f32_16x16x32_bf16(a, Wf[ks][1], acc2[1], 0, 0, 0);
            }
#pragma unroll
            for (int i = 0; i < 4; ++i) {
                const int t = t0 + s * kTS + lg * 4 + i;
                float* orow = out + ((size_t)(1 + t) * kBATCH + bglob + mtY) * kNY +
                              (w >> 1) * 32 + lw;
                orow[0]  = acc2[0][i] + bias[0];
                orow[16] = acc2[1][i] + bias[1];
            }
        }
    }

    if constexpr (!FINAL) {
#pragma unroll
        for (int mt = 0; mt < 2; ++mt)
#pragma unroll
            for (int d = 0; d < 2; ++d) {
                const int hm = w * 32 + d * 16 + lw;
                const size_t eb = ((size_t)c * kBATCH + bglob + mt) * kNH;
                ends[eb + hm]      = xr[mt][d];
                ends[eb + hm + kH] = xi[mt][d];
            }
    }
}

// ---------------------------------------------------------------------------
// Sequential combine over chunks + x0 computation.
// ---------------------------------------------------------------------------
__global__ __launch_bounds__(128) void combine_kernel(
    const float* __restrict__ y0, const float* __restrict__ Wy2x,
    const float* __restrict__ by2x, const float* __restrict__ lre,
    const float* __restrict__ lim, const float* __restrict__ ends,
    float* __restrict__ starts)
{
    const int b  = blockIdx.x;
    const int hm = threadIdx.x;

    const float ab = fabsf(lre[hm]);
    const float r  = expf(-ab);
    const float th = 1.5707963267948966f * lim[hm];
    float lr = r * cosf(th);
    float li = r * sinf(th);
    float pr = lr, pi = li;
#pragma unroll
    for (int k = 0; k < 6; ++k) {  // lambda^64
        const float nr = pr * pr - pi * pi;
        const float ni = 2.0f * pr * pi;
        pr = nr; pi = ni;
    }

    float s1 = by2x[hm];
    float s2 = by2x[hm + kH];
#pragma unroll 8
    for (int q = 0; q < kNY; ++q) {
        const float yv = y0[b * kNY + q];
        s1 = fmaf(Wy2x[hm * kNY + q], yv, s1);
        s2 = fmaf(Wy2x[(hm + kH) * kNY + q], yv, s2);
    }

    for (int c = 0; c < kNCHUNK; ++c) {
        const size_t base = ((size_t)c * kBATCH + b) * kNH;
        starts[base + hm]      = s1;
        starts[base + hm + kH] = s2;
        const float e1 = ends[base + hm];
        const float e2 = ends[base + hm + kH];
        const float n1 = fmaf(pr, s1, fmaf(-pi, s2, e1));
        const float n2 = fmaf(pi, s1, fmaf(pr, s2, e2));
        s1 = n1; s2 = n2;
    }
}

// Y row 0 = Wx2y @ x0 + bx2y  (x0 = starts[c=0])
__global__ __launch_bounds__(64) void y0_kernel(
    const float* __restrict__ starts, const float* __restrict__ Wx2y,
    const float* __restrict__ bx2y, float* __restrict__ out)
{
    const int b = blockIdx.x;
    const int y = threadIdx.x;
    const float* x0 = starts + (size_t)b * kNH;
    float acc = bx2y[y];
#pragma unroll 4
    for (int h = 0; h < kNH; h += 4) {
        float4 xv = *(const float4*)&x0[h];
        float4 wv = *(const float4*)&Wx2y[y * kNH + h];
        acc = fmaf(wv.x, xv.x, acc);
        acc = fmaf(wv.y, xv.y, acc);
        acc = fmaf(wv.z, xv.z, acc);
        acc = fmaf(wv.w, xv.w, acc);
    }
    out[(size_t)b * kNY + y] = acc;
}

extern "C" void kernel_launch(void* const* d_in, const int* in_sizes, int n_in,
                              void* d_out, int out_size, void* d_ws, size_t ws_size,
                              hipStream_t stream) {
    const float* y0   = (const float*)d_in[0];
    const float* U    = (const float*)d_in[1];
    const float* lre  = (const float*)d_in[2];
    const float* lim  = (const float*)d_in[3];
    const float* Bmat = (const float*)d_in[4];
    const float* Wy2x = (const float*)d_in[5];
    const float* by2x = (const float*)d_in[6];
    const float* Wx2y = (const float*)d_in[7];
    const float* bx2y = (const float*)d_in[8];
    float* out = (float*)d_out;

    float* ends   = (float*)d_ws;                          // 4 MB
    float* starts = ends + (size_t)kNCHUNK * kBATCH * kNH; // 4 MB

    const int grid = kNCHUNK * (kBATCH / 2);  // 2048 blocks

    scan_mfma<false><<<grid, 256, SMEM1, stream>>>(
        U, lre, lim, Bmat, nullptr, nullptr, nullptr, ends, nullptr);
    combine_kernel<<<kBATCH, 128, 0, stream>>>(
        y0, Wy2x, by2x, lre, lim, ends, starts);
    y0_kernel<<<kBATCH, 64, 0, stream>>>(starts, Wx2y, bx2y, out);
    scan_mfma<true><<<grid, 256, SMEM2, stream>>>(
        U, lre, lim, Bmat, Wx2y, bx2y, starts, nullptr, out);
}